// Round 6
// baseline (260.809 us; speedup 1.0000x reference)
//
#include <hip/hip_runtime.h>
#include <hip/hip_bf16.h>

#define T_DIM 4096
#define B_DIM 32
#define I_DIM 512
#define O_DIM 512
#define M_DIM (T_DIM * B_DIM)   // 131072
#define PARAM 0.1f
#define ISCALE 1.1111112f       // 1/(1-p)

#define STRIP 64
#define TAPS 8                  // p^8 = 1e-8 << bf16 eps

#define BM 64
#define BN 256
#define BK 64

typedef __attribute__((ext_vector_type(8))) short bf16x8;
typedef __attribute__((ext_vector_type(4))) float f32x4;

__device__ __forceinline__ unsigned short f2bf(float f) {
    union { __hip_bfloat16 b; unsigned short u; } cv;
    cv.b = __float2bfloat16(f);
    return cv.u;
}

// --- W fp32 -> bf16 (0.5 MB, ws offset 0) ---
__global__ __launch_bounds__(256) void wcvt_kernel(const float* __restrict__ W,
                                                   unsigned short* __restrict__ Wb) {
    const int i = (blockIdx.x * 256 + threadIdx.x) * 4;
    f32x4 v = *(const f32x4*)(W + i);
    ushort4 o;
    o.x = f2bf(v[0]); o.y = f2bf(v[1]); o.z = f2bf(v[2]); o.w = f2bf(v[3]);
    *(ushort4*)(Wb + i) = o;
}

// --- EMA over raw X (linearity: EMA(XW+b) = EMA(X)W + s[t]*b). Strip-parallel.
// STRIP=64 -> 1024 blocks (4 waves/SIMD) for latency hiding. Compact bf16 rows
// into d_ws. ---
__global__ __launch_bounds__(256) void xema_kernel(const float* __restrict__ X,
                                                   unsigned short* __restrict__ Xv) {
    const int s   = blockIdx.x >> 4;                 // strip 0..63
    const int blk = blockIdx.x & 15;
    const int col = (blk * 256 + threadIdx.x) * 4;   // within [b][o] plane
    const int t0  = s * STRIP;
    const int b   = col >> 9;
    const int o   = col & 511;

    const float* xin = X + (size_t)t0 * 16384 + col;
    unsigned short* xout = Xv + (size_t)(t0 * 32 + b) * 512 + o;

    f32x4 v = {0.f, 0.f, 0.f, 0.f};
    if (s > 0) {
        const float* w = xin - (size_t)TAPS * 16384;
        #pragma unroll
        for (int j = 0; j < TAPS; ++j)
            v = PARAM * v + *(const f32x4*)(w + (size_t)j * 16384);
    }

    f32x4 bufA[8], bufB[8];
    #pragma unroll
    for (int j = 0; j < 8; ++j) bufA[j] = *(const f32x4*)(xin + (size_t)j * 16384);

    #pragma unroll
    for (int i = 0; i < STRIP; i += 16) {
        #pragma unroll
        for (int j = 0; j < 8; ++j)
            bufB[j] = *(const f32x4*)(xin + (size_t)(i + 8 + j) * 16384);
        #pragma unroll
        for (int j = 0; j < 8; ++j) {
            v = PARAM * v + bufA[j];
            ushort4 pk; pk.x = f2bf(v[0]); pk.y = f2bf(v[1]); pk.z = f2bf(v[2]); pk.w = f2bf(v[3]);
            *(ushort4*)(xout + (size_t)(i + j) * 16384) = pk;
        }
        if (i + 16 < STRIP) {
            #pragma unroll
            for (int j = 0; j < 8; ++j)
                bufA[j] = *(const f32x4*)(xin + (size_t)(i + 16 + j) * 16384);
        }
        #pragma unroll
        for (int j = 0; j < 8; ++j) {
            v = PARAM * v + bufB[j];
            ushort4 pk; pk.x = f2bf(v[0]); pk.y = f2bf(v[1]); pk.z = f2bf(v[2]); pk.w = f2bf(v[3]);
            *(ushort4*)(xout + (size_t)(i + 8 + j) * 16384) = pk;
        }
    }
}

// --- GEMM: BM=64 x BN=256, BK=64, double-buffered LDS (80KB -> 2 blocks/CU,
// 4 waves/SIMD). Prefetch next K-tile via global_load_lds BEFORE computing the
// current one; the barrier's vmcnt(0) drain then overlaps compute. 8 waves,
// wave-tile 64x32 (acc 4x2). Pre-swizzled staging source (involution c^(r&7)). ---
__global__ __launch_bounds__(512, 4) void gemm_kernel(const unsigned short* __restrict__ Xv,
                                                      const unsigned short* __restrict__ Wb,
                                                      const float* __restrict__ bias,
                                                      float* __restrict__ Y) {
    __shared__ __align__(16) short As[2][BM * BK];   //  8 KB x2
    __shared__ __align__(16) short Bs[2][BN * BK];   // 32 KB x2

    const int tid  = threadIdx.x;
    const int lane = tid & 63;
    const int wave = tid >> 6;        // = wn, 0..7

    // 4096 blocks: xcd = bid&7; per XCD alternate bn then advance m ->
    // temporally-close blocks on one XCD share A rows and keep W L2-hot.
    const int bid = blockIdx.x;
    const int jj  = bid >> 3;                    // 0..511
    const int bn  = jj & 1;
    const int mt  = (bid & 7) * 256 + (jj >> 1); // 0..2047
    const int row0 = mt * BM;
    const int col0 = bn * BN;

    // Staging geometry (both A and B): chunk c = tid&7 within row, r&7 = (tid>>3)&7
    // for every chunk set -> swizzled source chunk cs is per-thread constant.
    const int cs = (tid & 7) ^ ((tid >> 3) & 7);
    const unsigned short* aSrc = Xv + (size_t)(row0 + (tid >> 3)) * 512 + cs * 8;
    const unsigned short* bSrc = Wb + (size_t)(col0 + (tid >> 3)) * 512 + cs * 8;

    #define STAGE(buf, k0)                                                          \
        do {                                                                        \
            __builtin_amdgcn_global_load_lds(                                       \
                (const __attribute__((address_space(1))) unsigned int*)(aSrc + (k0)),\
                (__attribute__((address_space(3))) unsigned int*)(&As[buf][0] + wave * 512), \
                16, 0, 0);                                                          \
            _Pragma("unroll")                                                       \
            for (int i_ = 0; i_ < 4; ++i_) {                                        \
                __builtin_amdgcn_global_load_lds(                                   \
                    (const __attribute__((address_space(1))) unsigned int*)(bSrc + (size_t)i_ * 64 * 512 + (k0)), \
                    (__attribute__((address_space(3))) unsigned int*)(&Bs[buf][0] + i_ * 4096 + wave * 512), \
                    16, 0, 0);                                                      \
            }                                                                       \
        } while (0)

    f32x4 acc[4][2] = {};

    STAGE(0, 0);
    __syncthreads();   // vmcnt(0): tile 0 ready

    #pragma unroll
    for (int ks = 0; ks < I_DIM / BK; ++ks) {
        const int cur = ks & 1;
        if (ks < I_DIM / BK - 1)
            STAGE(cur ^ 1, (ks + 1) * BK);   // async into other buffer

        #pragma unroll
        for (int kk = 0; kk < 2; ++kk) {
            const int cc = kk * 4 + (lane >> 4);
            bf16x8 a[4], b[2];
            #pragma unroll
            for (int mf = 0; mf < 4; ++mf) {
                const int r = mf * 16 + (lane & 15);
                a[mf] = *(const bf16x8*)((const char*)&As[cur][0] + r * 128 + ((cc ^ (r & 7)) << 4));
            }
            #pragma unroll
            for (int nf = 0; nf < 2; ++nf) {
                const int r = wave * 32 + nf * 16 + (lane & 15);
                b[nf] = *(const bf16x8*)((const char*)&Bs[cur][0] + r * 128 + ((cc ^ (r & 7)) << 4));
            }
            #pragma unroll
            for (int mf = 0; mf < 4; ++mf)
                #pragma unroll
                for (int nf = 0; nf < 2; ++nf)
                    acc[mf][nf] = __builtin_amdgcn_mfma_f32_16x16x32_bf16(
                        a[mf], b[nf], acc[mf][nf], 0, 0, 0);
        }
        __syncthreads();   // drains next-tile vmcnt; loads flew during compute
    }

    // bias EMA-scale s[t] = (1 - p^(t+1))/(1-p); t depends on (mf, j) only.
    float sc[4][4];
    #pragma unroll
    for (int mf = 0; mf < 4; ++mf)
        #pragma unroll
        for (int j = 0; j < 4; ++j) {
            const int t = (row0 + mf * 16 + ((lane >> 4) << 2) + j) >> 5;
            sc[mf][j] = (1.0f - __expf(-2.3025851f * (float)(t + 1))) * ISCALE;
        }

    #pragma unroll
    for (int mf = 0; mf < 4; ++mf) {
        #pragma unroll
        for (int nf = 0; nf < 2; ++nf) {
            const int gcol = col0 + wave * 32 + nf * 16 + (lane & 15);
            const float bv = bias[gcol];
            #pragma unroll
            for (int j = 0; j < 4; ++j) {
                const int grow = row0 + mf * 16 + ((lane >> 4) << 2) + j;
                Y[(size_t)grow * O_DIM + gcol] = acc[mf][nf][j] + sc[mf][j] * bv;
            }
        }
    }
}

extern "C" void kernel_launch(void* const* d_in, const int* in_sizes, int n_in,
                              void* d_out, int out_size, void* d_ws, size_t ws_size,
                              hipStream_t stream) {
    const float* X    = (const float*)d_in[0];
    const float* W    = (const float*)d_in[1];
    const float* bias = (const float*)d_in[2];
    float* Y = (float*)d_out;
    unsigned short* Wb = (unsigned short*)d_ws;                       // 512 KB
    unsigned short* Xv = (unsigned short*)((char*)d_ws + (1 << 20));  // 134 MB (ws ~1 GiB)

    wcvt_kernel<<<dim3(O_DIM * I_DIM / (256 * 4)), dim3(256), 0, stream>>>(W, Wb);
    xema_kernel<<<dim3((T_DIM / STRIP) * 16), dim3(256), 0, stream>>>(X, Xv);
    gemm_kernel<<<dim3((M_DIM / BM) * (O_DIM / BN)), dim3(512), 0, stream>>>(Xv, Wb, bias, Y);
}

// Round 7
// 240.504 us; speedup vs baseline: 1.0844x; 1.0844x over previous
//
#include <hip/hip_runtime.h>
#include <hip/hip_bf16.h>

#define T_DIM 4096
#define B_DIM 32
#define I_DIM 512
#define O_DIM 512
#define M_DIM (T_DIM * B_DIM)   // 131072
#define PARAM 0.1f
#define ISCALE 1.1111112f       // 1/(1-p)

#define STRIP 64
#define TAPS 8                  // p^8 = 1e-8 << bf16 eps

#define BM 128
#define BN 256
#define BK 64
#define NK (I_DIM / BK)         // 8

typedef __attribute__((ext_vector_type(8))) short bf16x8;
typedef __attribute__((ext_vector_type(4))) float f32x4;

__device__ __forceinline__ unsigned short f2bf(float f) {
    union { __hip_bfloat16 b; unsigned short u; } cv;
    cv.b = __float2bfloat16(f);
    return cv.u;
}

// --- W fp32 -> bf16 (0.5 MB, ws offset 0) ---
__global__ __launch_bounds__(256) void wcvt_kernel(const float* __restrict__ W,
                                                   unsigned short* __restrict__ Wb) {
    const int i = (blockIdx.x * 256 + threadIdx.x) * 4;
    f32x4 v = *(const f32x4*)(W + i);
    ushort4 o;
    o.x = f2bf(v[0]); o.y = f2bf(v[1]); o.z = f2bf(v[2]); o.w = f2bf(v[3]);
    *(ushort4*)(Wb + i) = o;
}

// --- EMA over raw X (linearity: EMA(XW+b) = EMA(X)W + s[t]*b). Strip-parallel,
// warm-up reads TAPS raw rows; bf16 output compacted into d_ws. ---
__global__ __launch_bounds__(256) void xema_kernel(const float* __restrict__ X,
                                                   unsigned short* __restrict__ Xv) {
    const int s   = blockIdx.x >> 4;                 // strip 0..63
    const int blk = blockIdx.x & 15;
    const int col = (blk * 256 + threadIdx.x) * 4;
    const int t0  = s * STRIP;
    const int b   = col >> 9;
    const int o   = col & 511;

    const float* xin = X + (size_t)t0 * 16384 + col;
    unsigned short* xout = Xv + (size_t)(t0 * 32 + b) * 512 + o;

    f32x4 v = {0.f, 0.f, 0.f, 0.f};
    if (s > 0) {
        const float* w = xin - (size_t)TAPS * 16384;
        #pragma unroll
        for (int j = 0; j < TAPS; ++j)
            v = PARAM * v + *(const f32x4*)(w + (size_t)j * 16384);
    }

    f32x4 bufA[8], bufB[8];
    #pragma unroll
    for (int j = 0; j < 8; ++j) bufA[j] = *(const f32x4*)(xin + (size_t)j * 16384);

    #pragma unroll
    for (int i = 0; i < STRIP; i += 16) {
        #pragma unroll
        for (int j = 0; j < 8; ++j)
            bufB[j] = *(const f32x4*)(xin + (size_t)(i + 8 + j) * 16384);
        #pragma unroll
        for (int j = 0; j < 8; ++j) {
            v = PARAM * v + bufA[j];
            ushort4 pk; pk.x = f2bf(v[0]); pk.y = f2bf(v[1]); pk.z = f2bf(v[2]); pk.w = f2bf(v[3]);
            *(ushort4*)(xout + (size_t)(i + j) * 16384) = pk;
        }
        if (i + 16 < STRIP) {
            #pragma unroll
            for (int j = 0; j < 8; ++j)
                bufA[j] = *(const f32x4*)(xin + (size_t)(i + 16 + j) * 16384);
        }
        #pragma unroll
        for (int j = 0; j < 8; ++j) {
            v = PARAM * v + bufB[j];
            ushort4 pk; pk.x = f2bf(v[0]); pk.y = f2bf(v[1]); pk.z = f2bf(v[2]); pk.w = f2bf(v[3]);
            *(ushort4*)(xout + (size_t)(i + 8 + j) * 16384) = pk;
        }
    }
}

// --- GEMM: 128x256 tile, BK=64, 3-deep LDS pipeline (144KB, 1 block/CU).
// T3+T4: counted vmcnt (12 -> oldest stage only), raw s_barrier, loads stay in
// flight across barriers. 8 waves, wave-tile 64x64 (acc 4x4). Pre-swizzled
// global_load_lds staging (involution c^(r&7)); swizzled ds_read. T5 setprio. ---
__global__ __launch_bounds__(512, 2) void gemm_kernel(const unsigned short* __restrict__ Xv,
                                                      const unsigned short* __restrict__ Wb,
                                                      const float* __restrict__ bias,
                                                      float* __restrict__ Y) {
    __shared__ __align__(16) short As[3][BM * BK];   // 16 KB x3
    __shared__ __align__(16) short Bs[3][BN * BK];   // 32 KB x3

    const int tid  = threadIdx.x;
    const int lane = tid & 63;
    const int wave = tid >> 6;        // 0..7
    const int wm   = wave >> 2;       // 0..1
    const int wn   = wave & 3;        // 0..3

    // 2048 blocks: xcd = bid&7; bn inner so the bn-pair sharing an A-panel runs
    // temporally close on one XCD (A fetched from HBM once, L2-served twice).
    const int bid = blockIdx.x;
    const int j   = bid >> 3;                     // 0..255
    const int bn  = j & 1;
    const int mt  = (bid & 7) * 128 + (j >> 1);   // 0..1023
    const int row0 = mt * BM;
    const int col0 = bn * BN;

    // Staging: 16B chunks, 8 per 128B row; r&7 = (tid>>3)&7 for every chunk-set
    // -> swizzled source chunk cs is per-thread constant.
    const int cs = (tid & 7) ^ ((tid >> 3) & 7);
    const unsigned short* aSrc = Xv + (size_t)(row0 + (tid >> 3)) * 512 + cs * 8;
    const unsigned short* bSrc = Wb + (size_t)(col0 + (tid >> 3)) * 512 + cs * 8;

    // 6 global_load_lds per thread per stage (A:2, B:4)
    #define STAGE(buf, k0)                                                            \
        do {                                                                          \
            _Pragma("unroll")                                                         \
            for (int it_ = 0; it_ < 2; ++it_)                                         \
                __builtin_amdgcn_global_load_lds(                                     \
                    (const __attribute__((address_space(1))) unsigned int*)(aSrc + (size_t)it_ * 64 * 512 + (k0)), \
                    (__attribute__((address_space(3))) unsigned int*)(&As[buf][0] + (it_ * 512 + wave * 64) * 8),  \
                    16, 0, 0);                                                        \
            _Pragma("unroll")                                                         \
            for (int it_ = 0; it_ < 4; ++it_)                                         \
                __builtin_amdgcn_global_load_lds(                                     \
                    (const __attribute__((address_space(1))) unsigned int*)(bSrc + (size_t)it_ * 64 * 512 + (k0)), \
                    (__attribute__((address_space(3))) unsigned int*)(&Bs[buf][0] + (it_ * 512 + wave * 64) * 8),  \
                    16, 0, 0);                                                        \
        } while (0)

    f32x4 acc[4][4] = {};

    #define COMPUTE(buf)                                                              \
        do {                                                                          \
            _Pragma("unroll")                                                         \
            for (int kk = 0; kk < 2; ++kk) {                                          \
                const int cc = kk * 4 + (lane >> 4);                                  \
                bf16x8 a_[4], b_[4];                                                  \
                _Pragma("unroll")                                                     \
                for (int mf = 0; mf < 4; ++mf) {                                      \
                    const int r = wm * 64 + mf * 16 + (lane & 15);                    \
                    a_[mf] = *(const bf16x8*)((const char*)&As[buf][0] + r * 128 + ((cc ^ (r & 7)) << 4)); \
                }                                                                     \
                _Pragma("unroll")                                                     \
                for (int nf = 0; nf < 4; ++nf) {                                      \
                    const int r = wn * 64 + nf * 16 + (lane & 15);                    \
                    b_[nf] = *(const bf16x8*)((const char*)&Bs[buf][0] + r * 128 + ((cc ^ (r & 7)) << 4)); \
                }                                                                     \
                __builtin_amdgcn_s_setprio(1);                                        \
                _Pragma("unroll")                                                     \
                for (int mf = 0; mf < 4; ++mf)                                        \
                    _Pragma("unroll")                                                 \
                    for (int nf = 0; nf < 4; ++nf)                                    \
                        acc[mf][nf] = __builtin_amdgcn_mfma_f32_16x16x32_bf16(        \
                            a_[mf], b_[nf], acc[mf][nf], 0, 0, 0);                    \
                __builtin_amdgcn_s_setprio(0);                                        \
            }                                                                         \
        } while (0)

    // One pipeline iteration: wait oldest stage (counted!), barrier, compute,
    // barrier (all reads of this buffer done), refill buffer with tile k+3.
    #define KITER(k, vm, buf)                                                         \
        do {                                                                          \
            asm volatile("s_waitcnt vmcnt(" #vm ")" ::: "memory");                    \
            __builtin_amdgcn_sched_barrier(0);                                        \
            __builtin_amdgcn_s_barrier();                                             \
            asm volatile("" ::: "memory");                                            \
            COMPUTE(buf);                                                             \
            asm volatile("" ::: "memory");                                            \
            __builtin_amdgcn_s_barrier();                                             \
            asm volatile("" ::: "memory");                                            \
            if ((k) + 3 < NK) STAGE(buf, ((k) + 3) * BK);                             \
        } while (0)

    STAGE(0, 0 * BK);
    STAGE(1, 1 * BK);
    STAGE(2, 2 * BK);

    KITER(0, 12, 0);
    KITER(1, 12, 1);
    KITER(2, 12, 2);
    KITER(3, 12, 0);
    KITER(4, 12, 1);
    KITER(5, 12, 2);
    KITER(6,  6, 0);
    KITER(7,  0, 1);

    // bias EMA-scale s[t] = (1 - p^(t+1))/(1-p); t depends on (mf, j) only.
    float sc[4][4];
    #pragma unroll
    for (int mf = 0; mf < 4; ++mf)
        #pragma unroll
        for (int jj = 0; jj < 4; ++jj) {
            const int t = (row0 + wm * 64 + mf * 16 + ((lane >> 4) << 2) + jj) >> 5;
            sc[mf][jj] = (1.0f - __expf(-2.3025851f * (float)(t + 1))) * ISCALE;
        }

    #pragma unroll
    for (int mf = 0; mf < 4; ++mf) {
        #pragma unroll
        for (int nf = 0; nf < 4; ++nf) {
            const int gcol = col0 + wn * 64 + nf * 16 + (lane & 15);
            const float bv = bias[gcol];
            #pragma unroll
            for (int jj = 0; jj < 4; ++jj) {
                const int grow = row0 + wm * 64 + mf * 16 + ((lane >> 4) << 2) + jj;
                Y[(size_t)grow * O_DIM + gcol] = acc[mf][nf][jj] + sc[mf][jj] * bv;
            }
        }
    }
}

extern "C" void kernel_launch(void* const* d_in, const int* in_sizes, int n_in,
                              void* d_out, int out_size, void* d_ws, size_t ws_size,
                              hipStream_t stream) {
    const float* X    = (const float*)d_in[0];
    const float* W    = (const float*)d_in[1];
    const float* bias = (const float*)d_in[2];
    float* Y = (float*)d_out;
    unsigned short* Wb = (unsigned short*)d_ws;                       // 512 KB
    unsigned short* Xv = (unsigned short*)((char*)d_ws + (1 << 20));  // 134 MB

    wcvt_kernel<<<dim3(O_DIM * I_DIM / (256 * 4)), dim3(256), 0, stream>>>(W, Wb);
    xema_kernel<<<dim3((T_DIM / STRIP) * 16), dim3(256), 0, stream>>>(X, Xv);
    gemm_kernel<<<dim3((M_DIM / BM) * (O_DIM / BN)), dim3(512), 0, stream>>>(Xv, Wb, bias, Y);
}